// Round 2
// 376.811 us; speedup vs baseline: 1.0781x; 1.0781x over previous
//
#include <hip/hip_runtime.h>
#include <stdint.h>

#define DIM 2048

typedef short short8 __attribute__((ext_vector_type(8)));
typedef float f32x4 __attribute__((ext_vector_type(4)));

__device__ __forceinline__ unsigned short f2bf(float f) {
    union { float f; unsigned int u; } v;
    v.f = f;
    unsigned int r = v.u + 0x7FFFu + ((v.u >> 16) & 1u);  // round-to-nearest-even
    return (unsigned short)(r >> 16);
}
__device__ __forceinline__ float bf2f(unsigned short u) {
    union { unsigned int u; float f; } v;
    v.u = ((unsigned int)u) << 16;
    return v.f;
}

// async global->LDS, 16B per lane. LDS dest must be wave-uniform base + lane*16.
__device__ __forceinline__ void async16(const unsigned short* g, unsigned short* l) {
    __builtin_amdgcn_global_load_lds(
        (__attribute__((address_space(1))) void*)(uintptr_t)g,
        (__attribute__((address_space(3))) void*)(uintptr_t)l,
        16, 0, 0);
}

// Tiled skew-symmetric build: one block per upper-tri 64x64 tile pair.
__global__ __launch_bounds__(256) void build_A_tiled(const float* __restrict__ ang,
                                                     unsigned short* __restrict__ A) {
    __shared__ float tile[64][65];
    int b = blockIdx.x;
    int ti = 0, rem = b;
    while (rem >= 32 - ti) { rem -= 32 - ti; ++ti; }
    const int tj = ti + rem;
    const int t  = threadIdx.x;
    const int lj = t & 63;
    const int lw = t >> 6;
    const bool diag = (ti == tj);

#pragma unroll
    for (int m = 0; m < 16; ++m) {
        const int li = lw * 16 + m;
        const int i = ti * 64 + li;
        const int j = tj * 64 + lj;
        float v = 0.0f;
        if (i < j) v = ang[i * (4095 - i) / 2 + (j - i - 1)];
        tile[li][lj] = v;
    }
    __syncthreads();

#pragma unroll
    for (int m = 0; m < 16; ++m) {
        const int li = lw * 16 + m;
        float v;
        if (diag) {
            if (li < lj)      v =  tile[li][lj];
            else if (li > lj) v = -tile[lj][li];
            else              v = 0.0f;
        } else {
            v = tile[li][lj];
        }
        A[(size_t)(ti * 64 + li) * DIM + tj * 64 + lj] = f2bf(v);
    }
    if (!diag) {
#pragma unroll
        for (int m = 0; m < 16; ++m) {
            const int li = lw * 16 + m;
            A[(size_t)(tj * 64 + li) * DIM + ti * 64 + lj] = f2bf(-tile[lj][li]);
        }
    }
}

// fp32 -> bf16, 4 elems/thread
__global__ void cvt_f32_bf16(const float* __restrict__ in, unsigned short* __restrict__ out) {
    int i = (blockIdx.x * 256 + threadIdx.x) * 4;
    const float4 v = *(const float4*)(in + i);
    ushort4 o;
    o.x = f2bf(v.x); o.y = f2bf(v.y); o.z = f2bf(v.z); o.w = f2bf(v.w);
    *(ushort4*)(out + i) = o;
}

// Wt builder: Wt[m*N+n] = (m==n) - 2*A[m*N+n] - sum_k A[m][k]*A[n][k]
// 64x64 tiles (grid 32x32 = 1024 blocks -> ~4 blocks/CU for latency hiding),
// BK=64, XOR swizzle, 256 threads = 4 waves 2x2, each wave 32x32 (2x2 mfma).
__global__ __launch_bounds__(256) void gemm_s64(
        const unsigned short* __restrict__ A,
        unsigned short* __restrict__ Wt) {
    __shared__ __align__(16) unsigned short ldsA[64 * 64];   // 8 KB
    __shared__ __align__(16) unsigned short ldsB[64 * 64];   // 8 KB
    const int K = DIM, N = DIM;

    const int t    = threadIdx.x;
    const int bn   = blockIdx.x * 64;
    const int bm   = blockIdx.y * 64;
    const int lane = t & 63;
    const int wave = t >> 6;
    const int waveM = (wave >> 1) * 32;
    const int waveN = (wave & 1) * 32;
    const int fm = lane & 15;
    const int fq = lane >> 4;

    f32x4 acc[2][2];
#pragma unroll
    for (int i = 0; i < 2; ++i)
#pragma unroll
        for (int j = 0; j < 2; ++j)
            acc[i][j] = (f32x4){0.f, 0.f, 0.f, 0.f};

    const int trow   = t >> 3;                  // 0..31
    const int tchunk = (t & 7) ^ (trow & 7);    // swizzled source k-chunk
    const unsigned short* gA = A + (size_t)(bm + trow) * K + tchunk * 8;
    const unsigned short* gB = A + (size_t)(bn + trow) * K + tchunk * 8;
    const size_t rowskip = (size_t)32 * K;
    unsigned short* lA = ldsA + t * 8;
    unsigned short* lB = ldsB + t * 8;

    for (int kt = 0; kt < K; kt += 64) {
        __syncthreads();
        async16(gA + kt, lA);
        async16(gA + kt + rowskip, lA + 2048);
        async16(gB + kt, lB);
        async16(gB + kt + rowskip, lB + 2048);
        __syncthreads();

#pragma unroll
        for (int ks = 0; ks < 2; ++ks) {
            short8 af[2], bfv[2];
#pragma unroll
            for (int i = 0; i < 2; ++i) {
                const int rowA = waveM + i * 16 + fm;
                const int rowB = waveN + i * 16 + fm;
                af[i]  = *(const short8*)(ldsA + rowA * 64 + (((ks << 2) + fq) ^ (rowA & 7)) * 8);
                bfv[i] = *(const short8*)(ldsB + rowB * 64 + (((ks << 2) + fq) ^ (rowB & 7)) * 8);
            }
#pragma unroll
            for (int i = 0; i < 2; ++i)
#pragma unroll
                for (int j = 0; j < 2; ++j)
                    acc[i][j] = __builtin_amdgcn_mfma_f32_16x16x32_bf16(
                        af[i], bfv[j], acc[i][j], 0, 0, 0);
        }
    }

#pragma unroll
    for (int i = 0; i < 2; ++i) {
#pragma unroll
        for (int j = 0; j < 2; ++j) {
            const int col = bn + waveN + j * 16 + fm;
#pragma unroll
            for (int r = 0; r < 4; ++r) {
                const int row = bm + waveM + i * 16 + fq * 4 + r;
                const float a = bf2f(A[(size_t)row * N + col]);
                const float w = (row == col ? 1.0f : 0.0f) - 2.0f * a - acc[i][j][r];
                Wt[(size_t)row * N + col] = f2bf(w);
            }
        }
    }
}

// ---------------------------------------------------------------------------
// Main NT GEMM, 256x256 tile, BK=64, 8-phase counted-vmcnt pipeline (T2+T3+T4+T5).
//   out[m*N+n] = sum_k x[m][k]*Wt[n][k] + bias[n]
// 512 threads = 8 waves (2M x 4N); per-wave output 128x64 (acc[8][4]).
// LDS: 2 buffers x (A 32KB + B 32KB) = 128KB, 1 block/CU.
// Per K-tile = 4 phases (C-quadrant each, 16 MFMA). B-frags for both j-halves
// cached in regs, so LDS half-regions die early:
//   Aalpha (rows {0-63,128-191}) read ph1 only; Balpha (rows 0-127) ph1;
//   Bbeta (rows 128-255) ph2; Abeta (rows {64-127,192-255}) ph3.
// -> staging of tile T+2 into the same buffer at phases 2,3,4 is race-free
// (each issue is after the end-of-phase barrier of its region's last reader).
// vmcnt(8) once per K-tile (phases 1,5): the 8 in-flight loads are the NEXT
// tile's 4 halves; everything older (this tile) is retired. Raw s_barrier,
// no vmcnt(0) in the main loop. Verified-conflict-free XOR swizzle kept:
// pre-swizzled global source + linear LDS dest + swizzled ds_read.
// ---------------------------------------------------------------------------

#define WAITV(N) asm volatile("s_waitcnt vmcnt(" #N ")" ::: "memory")
#define BAR() do { asm volatile("" ::: "memory"); __builtin_amdgcn_s_barrier(); asm volatile("" ::: "memory"); } while (0)

#define STG_A(BUF, R0, KT) async16(gA + (size_t)(R0) * 2048 + (KT), &ldsA[BUF][(R0) * 64 + t * 8])
#define STG_B(BUF, R0, KT) async16(gB + (size_t)(R0) * 2048 + (KT), &ldsB[BUF][(R0) * 64 + t * 8])

// A fragments for i-half IH: rows waveM + IH*64 + ii*16 + fm  (8x ds_read_b128)
#define READ_A(BUF, IH) do { \
    _Pragma("unroll") \
    for (int ii = 0; ii < 4; ++ii) { \
        const int row  = waveM + (IH) * 64 + ii * 16 + fm; \
        const int base = row * 64; \
        af[ii][0] = *(const short8*)(&ldsA[BUF][base + ((fq    ) ^ (row & 7)) * 8]); \
        af[ii][1] = *(const short8*)(&ldsA[BUF][base + ((fq + 4) ^ (row & 7)) * 8]); \
    } } while (0)

// B fragments for j-half JH: rows JH*128 + wn*32 + jj*16 + fm  (4x ds_read_b128)
#define READ_B(BUF, JH) do { \
    _Pragma("unroll") \
    for (int jj = 0; jj < 2; ++jj) { \
        const int row  = (JH) * 128 + wn * 32 + jj * 16 + fm; \
        const int base = row * 64; \
        bfr[JH][jj][0] = *(const short8*)(&ldsB[BUF][base + ((fq    ) ^ (row & 7)) * 8]); \
        bfr[JH][jj][1] = *(const short8*)(&ldsB[BUF][base + ((fq + 4) ^ (row & 7)) * 8]); \
    } } while (0)

#define MMAQ(IH, JH) do { \
    __builtin_amdgcn_s_setprio(1); \
    _Pragma("unroll") \
    for (int ks = 0; ks < 2; ++ks) \
    _Pragma("unroll") \
    for (int ii = 0; ii < 4; ++ii) \
    _Pragma("unroll") \
    for (int jj = 0; jj < 2; ++jj) \
        acc[(IH) * 4 + ii][(JH) * 2 + jj] = __builtin_amdgcn_mfma_f32_16x16x32_bf16( \
            af[ii][ks], bfr[JH][jj][ks], acc[(IH) * 4 + ii][(JH) * 2 + jj], 0, 0, 0); \
    __builtin_amdgcn_s_setprio(0); \
} while (0)

// One K-tile (4 phases). PRE: prefetch tile at k-elem KTN into same buffer.
#define KTILE(BUF, KTN, PRE, VN) do { \
    WAITV(VN); \
    BAR(); \
    /* phase 1: quad (0,0) — reads Aalpha + Balpha */ \
    READ_A(BUF, 0); \
    READ_B(BUF, 0); \
    MMAQ(0, 0); \
    BAR(); \
    /* phase 2: stage Aalpha(next); reads Bbeta */ \
    if (PRE) { STG_A(BUF, 0, KTN); STG_A(BUF, 128, KTN); } \
    READ_B(BUF, 1); \
    MMAQ(0, 1); \
    BAR(); \
    /* phase 3: stage Balpha(next); reads Abeta */ \
    if (PRE) { STG_B(BUF, 0, KTN); STG_B(BUF, 64, KTN); } \
    READ_A(BUF, 1); \
    MMAQ(1, 0); \
    BAR(); \
    /* phase 4: stage Bbeta + Abeta(next); no reads */ \
    if (PRE) { STG_B(BUF, 128, KTN); STG_B(BUF, 192, KTN); STG_A(BUF, 64, KTN); STG_A(BUF, 192, KTN); } \
    MMAQ(1, 1); \
    BAR(); \
} while (0)

__global__ __launch_bounds__(512, 2) void gemm_main(
        const unsigned short* __restrict__ Aop,   // x bf16 [M][K]
        const unsigned short* __restrict__ Bop,   // Wt bf16 [N][K]
        int M, int N, int K,
        const float* __restrict__ bias,
        float* __restrict__ out) {
    __shared__ __align__(16) unsigned short ldsA[2][256 * 64];  // 2 x 32 KB
    __shared__ __align__(16) unsigned short ldsB[2][256 * 64];  // 2 x 32 KB

    const int t    = threadIdx.x;
    const int bn   = blockIdx.x * 256;
    const int bm   = blockIdx.y * 256;
    const int lane = t & 63;
    const int wave = t >> 6;        // 0..7
    const int wm   = wave >> 2;     // 0..1
    const int wn   = wave & 3;      // 0..3
    const int waveM = wm * 128;
    const int fm = lane & 15;
    const int fq = lane >> 4;

    f32x4 acc[8][4];
#pragma unroll
    for (int i = 0; i < 8; ++i)
#pragma unroll
        for (int j = 0; j < 4; ++j)
            acc[i][j] = (f32x4){0.f, 0.f, 0.f, 0.f};

    short8 af[4][2];        // A frags, current i-half
    short8 bfr[2][2][2];    // B frags, both j-halves cached

    const int trow   = t >> 3;                  // 0..63
    const int tchunk = (t & 7) ^ (trow & 7);    // pre-swizzled source k-chunk
    const unsigned short* gA = Aop + (size_t)(bm + trow) * 2048 + tchunk * 8;
    const unsigned short* gB = Bop + (size_t)(bn + trow) * 2048 + tchunk * 8;

    // Prologue: stage tile 0 -> buf0, tile 1 -> buf1 (16 loads in flight).
    STG_A(0, 0, 0);   STG_A(0, 128, 0);  STG_B(0, 0, 0);   STG_B(0, 64, 0);
    STG_B(0, 128, 0); STG_B(0, 192, 0);  STG_A(0, 64, 0);  STG_A(0, 192, 0);
    STG_A(1, 0, 64);  STG_A(1, 128, 64); STG_B(1, 0, 64);  STG_B(1, 64, 64);
    STG_B(1, 128, 64);STG_B(1, 192, 64); STG_A(1, 64, 64); STG_A(1, 192, 64);

    // Main loop: 15 iterations x 2 K-tiles, full prefetch (tiles 2..31).
#pragma unroll 1
    for (int it = 0; it < 15; ++it) {
        const int kt = it * 128;
        KTILE(0, kt + 128, true, 8);   // compute tile 2it,   prefetch tile 2it+2
        KTILE(1, kt + 192, true, 8);   // compute tile 2it+1, prefetch tile 2it+3
    }
    // Tail: tiles 30,31 — no prefetch.
    KTILE(0, 0, false, 8);
    KTILE(1, 0, false, 0);

    // Epilogue: acc -> out (+bias). col mapping matches B frag remap.
#pragma unroll
    for (int i = 0; i < 8; ++i) {
        const int row0 = bm + waveM + i * 16 + fq * 4;
#pragma unroll
        for (int j = 0; j < 4; ++j) {
            const int col = bn + (j >> 1) * 128 + wn * 32 + (j & 1) * 16 + fm;
            const float b = bias[col];
#pragma unroll
            for (int r = 0; r < 4; ++r)
                out[(size_t)(row0 + r) * 2048 + col] = acc[i][j][r] + b;
        }
    }
}

extern "C" void kernel_launch(void* const* d_in, const int* in_sizes, int n_in,
                              void* d_out, int out_size, void* d_ws, size_t ws_size,
                              hipStream_t stream) {
    const float* x      = (const float*)d_in[0];   // 4*4096*2048
    const float* angles = (const float*)d_in[1];   // 2096128
    const float* bias   = (const float*)d_in[2];   // 2048
    float* out = (float*)d_out;

    char* ws = (char*)d_ws;
    unsigned short* Abf = (unsigned short*)ws;                      //  8 MB: A bf16
    unsigned short* Wt  = (unsigned short*)(ws + (8u << 20));       //  8 MB: W^T bf16
    unsigned short* xbf = (unsigned short*)(ws + (16u << 20));      // 64 MB: x bf16

    const int M = 4 * 4096;
    const int n_elem_x = M * DIM;

    build_A_tiled<<<528, 256, 0, stream>>>(angles, Abf);
    cvt_f32_bf16<<<(n_elem_x / 4) / 256, 256, 0, stream>>>(x, xbf);

    // Wt = I - 2A - A*A^T  (2048^3, 1024 blocks)
    gemm_s64<<<dim3(DIM / 64, DIM / 64), 256, 0, stream>>>(Abf, Wt);

    // out = x @ W + bias via NT against Wt (16384 x 2048 x 2048), 256^2 8-phase
    gemm_main<<<dim3(DIM / 256, M / 256), 512, 0, stream>>>(
        xbf, Wt, M, DIM, DIM, bias, out);
}

// Round 4
// 371.286 us; speedup vs baseline: 1.0941x; 1.0149x over previous
//
#include <hip/hip_runtime.h>
#include <stdint.h>

#define DIM 2048

typedef short short8 __attribute__((ext_vector_type(8)));
typedef float f32x4 __attribute__((ext_vector_type(4)));

__device__ __forceinline__ unsigned short f2bf(float f) {
    union { float f; unsigned int u; } v;
    v.f = f;
    unsigned int r = v.u + 0x7FFFu + ((v.u >> 16) & 1u);  // round-to-nearest-even
    return (unsigned short)(r >> 16);
}
__device__ __forceinline__ float bf2f(unsigned short u) {
    union { unsigned int u; float f; } v;
    v.u = ((unsigned int)u) << 16;
    return v.f;
}

// async global->LDS, 16B per lane. LDS dest must be wave-uniform base + lane*16.
__device__ __forceinline__ void async16(const unsigned short* g, unsigned short* l) {
    __builtin_amdgcn_global_load_lds(
        (__attribute__((address_space(1))) void*)(uintptr_t)g,
        (__attribute__((address_space(3))) void*)(uintptr_t)l,
        16, 0, 0);
}

// Tiled skew-symmetric build: one block per upper-tri 64x64 tile pair.
__global__ __launch_bounds__(256) void build_A_tiled(const float* __restrict__ ang,
                                                     unsigned short* __restrict__ A) {
    __shared__ float tile[64][65];
    int b = blockIdx.x;
    int ti = 0, rem = b;
    while (rem >= 32 - ti) { rem -= 32 - ti; ++ti; }
    const int tj = ti + rem;
    const int t  = threadIdx.x;
    const int lj = t & 63;
    const int lw = t >> 6;
    const bool diag = (ti == tj);

#pragma unroll
    for (int m = 0; m < 16; ++m) {
        const int li = lw * 16 + m;
        const int i = ti * 64 + li;
        const int j = tj * 64 + lj;
        float v = 0.0f;
        if (i < j) v = ang[i * (4095 - i) / 2 + (j - i - 1)];
        tile[li][lj] = v;
    }
    __syncthreads();

#pragma unroll
    for (int m = 0; m < 16; ++m) {
        const int li = lw * 16 + m;
        float v;
        if (diag) {
            if (li < lj)      v =  tile[li][lj];
            else if (li > lj) v = -tile[lj][li];
            else              v = 0.0f;
        } else {
            v = tile[li][lj];
        }
        A[(size_t)(ti * 64 + li) * DIM + tj * 64 + lj] = f2bf(v);
    }
    if (!diag) {
#pragma unroll
        for (int m = 0; m < 16; ++m) {
            const int li = lw * 16 + m;
            A[(size_t)(tj * 64 + li) * DIM + ti * 64 + lj] = f2bf(-tile[lj][li]);
        }
    }
}

// fp32 -> bf16, 4 elems/thread
__global__ void cvt_f32_bf16(const float* __restrict__ in, unsigned short* __restrict__ out) {
    int i = (blockIdx.x * 256 + threadIdx.x) * 4;
    const float4 v = *(const float4*)(in + i);
    ushort4 o;
    o.x = f2bf(v.x); o.y = f2bf(v.y); o.z = f2bf(v.z); o.w = f2bf(v.w);
    *(ushort4*)(out + i) = o;
}

// Wt builder: Wt[m*N+n] = (m==n) - 2*A[m*N+n] - sum_k A[m][k]*A[n][k]
// 64x64 tiles, BK=64, XOR swizzle, 256 threads = 4 waves 2x2, wave 32x32.
// XCD-aware swizzle: 1024 blocks, XCD k gets contiguous work chunk.
__global__ __launch_bounds__(256) void gemm_s64(
        const unsigned short* __restrict__ A,
        unsigned short* __restrict__ Wt) {
    __shared__ __align__(16) unsigned short ldsA[64 * 64];   // 8 KB
    __shared__ __align__(16) unsigned short ldsB[64 * 64];   // 8 KB
    const int K = DIM, N = DIM;

    const int t    = threadIdx.x;
    const int flat = blockIdx.y * 32 + blockIdx.x;           // 0..1023
    const int swz  = (flat & 7) * 128 + (flat >> 3);         // bijective (1024%8==0)
    const int bn   = (swz & 31) * 64;
    const int bm   = (swz >> 5) * 64;
    const int lane = t & 63;
    const int wave = t >> 6;
    const int waveM = (wave >> 1) * 32;
    const int waveN = (wave & 1) * 32;
    const int fm = lane & 15;
    const int fq = lane >> 4;

    f32x4 acc[2][2];
#pragma unroll
    for (int i = 0; i < 2; ++i)
#pragma unroll
        for (int j = 0; j < 2; ++j)
            acc[i][j] = (f32x4){0.f, 0.f, 0.f, 0.f};

    const int trow   = t >> 3;                  // 0..31
    const int tchunk = (t & 7) ^ (trow & 7);    // swizzled source k-chunk
    const unsigned short* gA = A + (size_t)(bm + trow) * K + tchunk * 8;
    const unsigned short* gB = A + (size_t)(bn + trow) * K + tchunk * 8;
    const size_t rowskip = (size_t)32 * K;
    unsigned short* lA = ldsA + t * 8;
    unsigned short* lB = ldsB + t * 8;

    for (int kt = 0; kt < K; kt += 64) {
        __syncthreads();
        async16(gA + kt, lA);
        async16(gA + kt + rowskip, lA + 2048);
        async16(gB + kt, lB);
        async16(gB + kt + rowskip, lB + 2048);
        __syncthreads();

#pragma unroll
        for (int ks = 0; ks < 2; ++ks) {
            short8 af[2], bfv[2];
#pragma unroll
            for (int i = 0; i < 2; ++i) {
                const int rowA = waveM + i * 16 + fm;
                const int rowB = waveN + i * 16 + fm;
                af[i]  = *(const short8*)(ldsA + rowA * 64 + (((ks << 2) + fq) ^ (rowA & 7)) * 8);
                bfv[i] = *(const short8*)(ldsB + rowB * 64 + (((ks << 2) + fq) ^ (rowB & 7)) * 8);
            }
#pragma unroll
            for (int i = 0; i < 2; ++i)
#pragma unroll
                for (int j = 0; j < 2; ++j)
                    acc[i][j] = __builtin_amdgcn_mfma_f32_16x16x32_bf16(
                        af[i], bfv[j], acc[i][j], 0, 0, 0);
        }
    }

#pragma unroll
    for (int i = 0; i < 2; ++i) {
#pragma unroll
        for (int j = 0; j < 2; ++j) {
            const int col = bn + waveN + j * 16 + fm;
#pragma unroll
            for (int r = 0; r < 4; ++r) {
                const int row = bm + waveM + i * 16 + fq * 4 + r;
                const float a = bf2f(A[(size_t)row * N + col]);
                const float w = (row == col ? 1.0f : 0.0f) - 2.0f * a - acc[i][j][r];
                Wt[(size_t)row * N + col] = f2bf(w);
            }
        }
    }
}

// ---------------------------------------------------------------------------
// Main NT GEMM, 256x256 tile, BK=64, balanced 4-phase counted-vmcnt pipeline.
// Every phase: [optional WAITV][BAR][stage 2-4 segs][16 MFMA][4-8 ds_reads for
// NEXT quadrant] -> every read batch is consumed >=1 barrier later (m201's
// proven read/consume relationship), reads balanced 4/8/4/8 per phase.
// Tile-boundary wait is vmcnt(6) at P3 (retires tile T+1's 8 loads, keeps
// T+2's 6 issued-so-far in flight) so P3/P4 pre-read T+1's B0/A0 fragments.
// Register-neutral: af single-buffered (WAR vs MFMA resolved by program
// order), bfr[half] may hold different tiles' halves.
// Region-death ledger (per tile T, buf b):
//   A0(T),B0(T) read at T-1 P3/P4 -> staged over in P1 (after P1 BAR).
//   B1(T) read end of P1          -> staged over in P2 (after P2 BAR).
//   A1(T) read end of P2          -> staged over in P3 (after P3 BAR).
//   T+1 B0/A0 reads (P3/P4) are after WAITV(6)+BAR; next overwrite of those
//   regions is T+1's P1 (after its BAR).
// XCD swizzle: 512 blocks, XCD k owns y-panels [8k,8k+8) x all bx -> x-panels
// fetched once per XCD (FETCH_SIZE should drop ~40%).
// ---------------------------------------------------------------------------

#define WAITV(N) asm volatile("s_waitcnt vmcnt(" #N ")" ::: "memory")
#define BAR() do { asm volatile("" ::: "memory"); __builtin_amdgcn_s_barrier(); asm volatile("" ::: "memory"); } while (0)

#define STG_A(BUF, R0, KT) async16(gA + (size_t)(R0) * 2048 + (KT), &ldsA[BUF][(R0) * 64 + t * 8])
#define STG_B(BUF, R0, KT) async16(gB + (size_t)(R0) * 2048 + (KT), &ldsB[BUF][(R0) * 64 + t * 8])

// A fragments for i-half IH into af (8x ds_read_b128)
#define READ_A_(BUF, IH) do { \
    _Pragma("unroll") \
    for (int ii = 0; ii < 4; ++ii) { \
        const int row  = waveM + (IH) * 64 + ii * 16 + fm; \
        const int base = row * 64; \
        af[ii][0] = *(const short8*)(&ldsA[BUF][base + ((fq    ) ^ (row & 7)) * 8]); \
        af[ii][1] = *(const short8*)(&ldsA[BUF][base + ((fq + 4) ^ (row & 7)) * 8]); \
    } } while (0)

// B fragments for j-half JH into bfr[JH] (4x ds_read_b128)
#define READ_B_(BUF, JH) do { \
    _Pragma("unroll") \
    for (int jj = 0; jj < 2; ++jj) { \
        const int row  = (JH) * 128 + wn * 32 + jj * 16 + fm; \
        const int base = row * 64; \
        bfr[JH][jj][0] = *(const short8*)(&ldsB[BUF][base + ((fq    ) ^ (row & 7)) * 8]); \
        bfr[JH][jj][1] = *(const short8*)(&ldsB[BUF][base + ((fq + 4) ^ (row & 7)) * 8]); \
    } } while (0)

#define MMAQ(IH, JH) do { \
    __builtin_amdgcn_s_setprio(1); \
    _Pragma("unroll") \
    for (int ks = 0; ks < 2; ++ks) \
    _Pragma("unroll") \
    for (int ii = 0; ii < 4; ++ii) \
    _Pragma("unroll") \
    for (int jj = 0; jj < 2; ++jj) \
        acc[(IH) * 4 + ii][(JH) * 2 + jj] = __builtin_amdgcn_mfma_f32_16x16x32_bf16( \
            af[ii][ks], bfr[JH][jj][ks], acc[(IH) * 4 + ii][(JH) * 2 + jj], 0, 0, 0); \
    __builtin_amdgcn_s_setprio(0); \
} while (0)

// One K-tile. PRE: prefetch tile T+2 (k-elem KTN) into same buffer.
// VN: vmcnt arg at P3 (6 steady; 0 for tile 30). NXT: pre-read tile T+1 frags.
#define TILE(BUF, KTN, PRE, VN, NXT) do { \
    /* P1: quad (0,0) */ \
    BAR(); \
    if (PRE) { STG_A(BUF, 0, KTN); STG_A(BUF, 128, KTN); STG_B(BUF, 0, KTN); STG_B(BUF, 64, KTN); } \
    MMAQ(0, 0); \
    READ_B_(BUF, 1); \
    /* P2: quad (0,1) */ \
    BAR(); \
    if (PRE) { STG_B(BUF, 128, KTN); STG_B(BUF, 192, KTN); } \
    MMAQ(0, 1); \
    READ_A_(BUF, 1); \
    /* P3: quad (1,0) */ \
    WAITV(VN); \
    BAR(); \
    if (PRE) { STG_A(BUF, 64, KTN); STG_A(BUF, 192, KTN); } \
    MMAQ(1, 0); \
    if (NXT) READ_B_((BUF) ^ 1, 0); \
    /* P4: quad (1,1) */ \
    BAR(); \
    MMAQ(1, 1); \
    if (NXT) READ_A_((BUF) ^ 1, 0); \
} while (0)

#define TILE_LAST(BUF) do { \
    BAR(); MMAQ(0, 0); READ_B_(BUF, 1); \
    BAR(); MMAQ(0, 1); READ_A_(BUF, 1); \
    BAR(); MMAQ(1, 0); \
    MMAQ(1, 1); \
} while (0)

__global__ __launch_bounds__(512, 2) void gemm_main(
        const unsigned short* __restrict__ Aop,   // x bf16 [M][K]
        const unsigned short* __restrict__ Bop,   // Wt bf16 [N][K]
        int M, int N, int K,
        const float* __restrict__ bias,
        float* __restrict__ out) {
    __shared__ __align__(16) unsigned short ldsA[2][256 * 64];  // 2 x 32 KB
    __shared__ __align__(16) unsigned short ldsB[2][256 * 64];  // 2 x 32 KB

    const int t    = threadIdx.x;
    // XCD-aware bijective swizzle over the 8x64 grid (512 blocks, 512%8==0).
    const int flat = blockIdx.y * 8 + blockIdx.x;
    const int swz  = (flat & 7) * 64 + (flat >> 3);
    const int bn   = (swz & 7) * 256;
    const int bm   = (swz >> 3) * 256;
    const int lane = t & 63;
    const int wave = t >> 6;        // 0..7
    const int wm   = wave >> 2;     // 0..1
    const int wn   = wave & 3;      // 0..3
    const int waveM = wm * 128;
    const int fm = lane & 15;
    const int fq = lane >> 4;

    f32x4 acc[8][4];
#pragma unroll
    for (int i = 0; i < 8; ++i)
#pragma unroll
        for (int j = 0; j < 4; ++j)
            acc[i][j] = (f32x4){0.f, 0.f, 0.f, 0.f};

    short8 af[4][2];        // A frags, current i-half (single-buffered)
    short8 bfr[2][2][2];    // B frags per j-half (may hold different tiles)

    const int trow   = t >> 3;                  // 0..63
    const int tchunk = (t & 7) ^ (trow & 7);    // pre-swizzled source k-chunk
    const unsigned short* gA = Aop + (size_t)(bm + trow) * 2048 + tchunk * 8;
    const unsigned short* gB = Bop + (size_t)(bn + trow) * 2048 + tchunk * 8;

    // Prologue: stage tile 0 -> buf0 (8 oldest), tile 1 -> buf1.
    STG_A(0, 0, 0);   STG_A(0, 128, 0);  STG_B(0, 0, 0);   STG_B(0, 64, 0);
    STG_B(0, 128, 0); STG_B(0, 192, 0);  STG_A(0, 64, 0);  STG_A(0, 192, 0);
    STG_A(1, 0, 64);  STG_A(1, 128, 64); STG_B(1, 0, 64);  STG_B(1, 64, 64);
    STG_B(1, 128, 64);STG_B(1, 192, 64); STG_A(1, 64, 64); STG_A(1, 192, 64);
    WAITV(8);           // tile 0's 8 retired; tile 1's 8 in flight
    BAR();
    READ_A_(0, 0);      // af   = A0(tile 0)
    READ_B_(0, 0);      // bfr0 = B0(tile 0)

    // Main loop: tiles 0..29, full prefetch of tiles 2..31.
#pragma unroll 1
    for (int it = 0; it < 15; ++it) {
        const int kt = it * 128;
        TILE(0, kt + 128, 1, 6, 1);   // tile 2it,   prefetch 2it+2
        TILE(1, kt + 192, 1, 6, 1);   // tile 2it+1, prefetch 2it+3
    }
    // Tail: tile 30 (wait out tile 31's loads at P3), tile 31.
    TILE(0, 0, 0, 0, 1);
    TILE_LAST(1);

    // Epilogue: acc -> out (+bias). col mapping matches B frag remap.
#pragma unroll
    for (int i = 0; i < 8; ++i) {
        const int row0 = bm + waveM + i * 16 + fq * 4;
#pragma unroll
        for (int j = 0; j < 4; ++j) {
            const int col = bn + (j >> 1) * 128 + wn * 32 + (j & 1) * 16 + fm;
            const float b = bias[col];
#pragma unroll
            for (int r = 0; r < 4; ++r)
                out[(size_t)(row0 + r) * 2048 + col] = acc[i][j][r] + b;
        }
    }
}

extern "C" void kernel_launch(void* const* d_in, const int* in_sizes, int n_in,
                              void* d_out, int out_size, void* d_ws, size_t ws_size,
                              hipStream_t stream) {
    const float* x      = (const float*)d_in[0];   // 4*4096*2048
    const float* angles = (const float*)d_in[1];   // 2096128
    const float* bias   = (const float*)d_in[2];   // 2048
    float* out = (float*)d_out;

    char* ws = (char*)d_ws;
    unsigned short* Abf = (unsigned short*)ws;                      //  8 MB: A bf16
    unsigned short* Wt  = (unsigned short*)(ws + (8u << 20));       //  8 MB: W^T bf16
    unsigned short* xbf = (unsigned short*)(ws + (16u << 20));      // 64 MB: x bf16

    const int M = 4 * 4096;
    const int n_elem_x = M * DIM;

    build_A_tiled<<<528, 256, 0, stream>>>(angles, Abf);
    cvt_f32_bf16<<<(n_elem_x / 4) / 256, 256, 0, stream>>>(x, xbf);

    // Wt = I - 2A - A*A^T  (2048^3, 1024 blocks)
    gemm_s64<<<dim3(DIM / 64, DIM / 64), 256, 0, stream>>>(Abf, Wt);

    // out = x @ W + bias via NT against Wt (16384 x 2048 x 2048)
    gemm_main<<<dim3(DIM / 256, M / 256), 512, 0, stream>>>(
        xbf, Wt, M, DIM, DIM, bias, out);
}

// Round 5
// 368.902 us; speedup vs baseline: 1.1012x; 1.0065x over previous
//
#include <hip/hip_runtime.h>
#include <stdint.h>

#define DIM 2048

typedef short short8 __attribute__((ext_vector_type(8)));
typedef float f32x4 __attribute__((ext_vector_type(4)));

__device__ __forceinline__ unsigned short f2bf(float f) {
    union { float f; unsigned int u; } v;
    v.f = f;
    unsigned int r = v.u + 0x7FFFu + ((v.u >> 16) & 1u);  // round-to-nearest-even
    return (unsigned short)(r >> 16);
}
__device__ __forceinline__ float bf2f(unsigned short u) {
    union { unsigned int u; float f; } v;
    v.u = ((unsigned int)u) << 16;
    return v.f;
}

// async global->LDS, 16B per lane. LDS dest must be wave-uniform base + lane*16.
__device__ __forceinline__ void async16(const unsigned short* g, unsigned short* l) {
    __builtin_amdgcn_global_load_lds(
        (__attribute__((address_space(1))) void*)(uintptr_t)g,
        (__attribute__((address_space(3))) void*)(uintptr_t)l,
        16, 0, 0);
}

// ---------------------------------------------------------------------------
// Merged prep kernel: blocks [0, NCVT) do fp32->bf16 conversion of x;
// blocks [NCVT, NCVT+528) build the skew-symmetric A in bf16.
// Independent outputs, per-block-uniform branch; merging removes one launch
// gap and overlaps build_A's small work under cvt's BW streaming.
// ---------------------------------------------------------------------------
#define NCVT 32768

__global__ __launch_bounds__(256) void prep_fused(const float* __restrict__ x,
                                                  unsigned short* __restrict__ xbf,
                                                  const float* __restrict__ ang,
                                                  unsigned short* __restrict__ A) {
    __shared__ float tile[64][65];
    if (blockIdx.x < NCVT) {
        // fp32 -> bf16, 4 elems/thread
        const int i = (blockIdx.x * 256 + threadIdx.x) * 4;
        const float4 v = *(const float4*)(x + i);
        ushort4 o;
        o.x = f2bf(v.x); o.y = f2bf(v.y); o.z = f2bf(v.z); o.w = f2bf(v.w);
        *(ushort4*)(xbf + i) = o;
        return;
    }
    // skew-symmetric build: one block per upper-tri 64x64 tile pair.
    int b = blockIdx.x - NCVT;
    int ti = 0, rem = b;
    while (rem >= 32 - ti) { rem -= 32 - ti; ++ti; }
    const int tj = ti + rem;
    const int t  = threadIdx.x;
    const int lj = t & 63;
    const int lw = t >> 6;
    const bool diag = (ti == tj);

#pragma unroll
    for (int m = 0; m < 16; ++m) {
        const int li = lw * 16 + m;
        const int i = ti * 64 + li;
        const int j = tj * 64 + lj;
        float v = 0.0f;
        if (i < j) v = ang[i * (4095 - i) / 2 + (j - i - 1)];
        tile[li][lj] = v;
    }
    __syncthreads();

#pragma unroll
    for (int m = 0; m < 16; ++m) {
        const int li = lw * 16 + m;
        float v;
        if (diag) {
            if (li < lj)      v =  tile[li][lj];
            else if (li > lj) v = -tile[lj][li];
            else              v = 0.0f;
        } else {
            v = tile[li][lj];
        }
        A[(size_t)(ti * 64 + li) * DIM + tj * 64 + lj] = f2bf(v);
    }
    if (!diag) {
#pragma unroll
        for (int m = 0; m < 16; ++m) {
            const int li = lw * 16 + m;
            A[(size_t)(tj * 64 + li) * DIM + ti * 64 + lj] = f2bf(-tile[lj][li]);
        }
    }
}

// ---------------------------------------------------------------------------
// Wt builder: Wt[m*N+n] = (m==n) - 2*A[m*N+n] - sum_k A[m][k]*A[n][k]
// 128x64 tiles (grid 16x32 = 512 blocks -> 2 blocks/CU for barrier overlap),
// BK=64, XOR swizzle, 256 threads = 4 waves (2M x 2N), wave = 64x32 output
// (acc[4][2]) -> 16 MFMA : 12 ds_read_b128 per wave per K-step (was 8:8).
// XCD-aware bijective swizzle (512 % 8 == 0).
// ---------------------------------------------------------------------------
__global__ __launch_bounds__(256) void gemm_s64(
        const unsigned short* __restrict__ A,
        unsigned short* __restrict__ Wt) {
    __shared__ __align__(16) unsigned short ldsA[128 * 64];  // 16 KB
    __shared__ __align__(16) unsigned short ldsB[64 * 64];   //  8 KB
    const int K = DIM, N = DIM;

    const int t    = threadIdx.x;
    const int flat = blockIdx.y * 32 + blockIdx.x;           // 0..511
    const int swz  = (flat & 7) * 64 + (flat >> 3);          // bijective
    const int bn   = (swz & 31) * 64;
    const int bm   = (swz >> 5) * 128;
    const int lane = t & 63;
    const int wave = t >> 6;
    const int waveM = (wave >> 1) * 64;
    const int waveN = (wave & 1) * 32;
    const int fm = lane & 15;
    const int fq = lane >> 4;

    f32x4 acc[4][2];
#pragma unroll
    for (int i = 0; i < 4; ++i)
#pragma unroll
        for (int j = 0; j < 2; ++j)
            acc[i][j] = (f32x4){0.f, 0.f, 0.f, 0.f};

    const int trow   = t >> 3;                  // 0..31
    const int tchunk = (t & 7) ^ (trow & 7);    // swizzled source k-chunk
    const unsigned short* gA = A + (size_t)(bm + trow) * K + tchunk * 8;
    const unsigned short* gB = A + (size_t)(bn + trow) * K + tchunk * 8;
    const size_t rowskip = (size_t)32 * K;
    unsigned short* lA = ldsA + t * 8;
    unsigned short* lB = ldsB + t * 8;

    for (int kt = 0; kt < K; kt += 64) {
        __syncthreads();
        async16(gA + kt,                lA);
        async16(gA + kt +     rowskip,  lA + 2048);
        async16(gA + kt + 2 * rowskip,  lA + 4096);
        async16(gA + kt + 3 * rowskip,  lA + 6144);
        async16(gB + kt,                lB);
        async16(gB + kt +     rowskip,  lB + 2048);
        __syncthreads();

#pragma unroll
        for (int ks = 0; ks < 2; ++ks) {
            short8 af[4], bfv[2];
#pragma unroll
            for (int i = 0; i < 4; ++i) {
                const int rowA = waveM + i * 16 + fm;
                af[i] = *(const short8*)(ldsA + rowA * 64 + (((ks << 2) + fq) ^ (rowA & 7)) * 8);
            }
#pragma unroll
            for (int j = 0; j < 2; ++j) {
                const int rowB = waveN + j * 16 + fm;
                bfv[j] = *(const short8*)(ldsB + rowB * 64 + (((ks << 2) + fq) ^ (rowB & 7)) * 8);
            }
#pragma unroll
            for (int i = 0; i < 4; ++i)
#pragma unroll
                for (int j = 0; j < 2; ++j)
                    acc[i][j] = __builtin_amdgcn_mfma_f32_16x16x32_bf16(
                        af[i], bfv[j], acc[i][j], 0, 0, 0);
        }
    }

#pragma unroll
    for (int i = 0; i < 4; ++i) {
#pragma unroll
        for (int j = 0; j < 2; ++j) {
            const int col = bn + waveN + j * 16 + fm;
#pragma unroll
            for (int r = 0; r < 4; ++r) {
                const int row = bm + waveM + i * 16 + fq * 4 + r;
                const float a = bf2f(A[(size_t)row * N + col]);
                const float w = (row == col ? 1.0f : 0.0f) - 2.0f * a - acc[i][j][r];
                Wt[(size_t)row * N + col] = f2bf(w);
            }
        }
    }
}

// ---------------------------------------------------------------------------
// Main NT GEMM, 256x256 tile, BK=64, balanced 4-phase counted-vmcnt pipeline.
// (unchanged from the 120.0 us / MfmaUtil 49 / FETCH 98.5 MB passing version)
// ---------------------------------------------------------------------------

#define WAITV(N) asm volatile("s_waitcnt vmcnt(" #N ")" ::: "memory")
#define BAR() do { asm volatile("" ::: "memory"); __builtin_amdgcn_s_barrier(); asm volatile("" ::: "memory"); } while (0)

#define STG_A(BUF, R0, KT) async16(gA + (size_t)(R0) * 2048 + (KT), &ldsA[BUF][(R0) * 64 + t * 8])
#define STG_B(BUF, R0, KT) async16(gB + (size_t)(R0) * 2048 + (KT), &ldsB[BUF][(R0) * 64 + t * 8])

// A fragments for i-half IH into af (8x ds_read_b128)
#define READ_A_(BUF, IH) do { \
    _Pragma("unroll") \
    for (int ii = 0; ii < 4; ++ii) { \
        const int row  = waveM + (IH) * 64 + ii * 16 + fm; \
        const int base = row * 64; \
        af[ii][0] = *(const short8*)(&ldsA[BUF][base + ((fq    ) ^ (row & 7)) * 8]); \
        af[ii][1] = *(const short8*)(&ldsA[BUF][base + ((fq + 4) ^ (row & 7)) * 8]); \
    } } while (0)

// B fragments for j-half JH into bfr[JH] (4x ds_read_b128)
#define READ_B_(BUF, JH) do { \
    _Pragma("unroll") \
    for (int jj = 0; jj < 2; ++jj) { \
        const int row  = (JH) * 128 + wn * 32 + jj * 16 + fm; \
        const int base = row * 64; \
        bfr[JH][jj][0] = *(const short8*)(&ldsB[BUF][base + ((fq    ) ^ (row & 7)) * 8]); \
        bfr[JH][jj][1] = *(const short8*)(&ldsB[BUF][base + ((fq + 4) ^ (row & 7)) * 8]); \
    } } while (0)

#define MMAQ(IH, JH) do { \
    __builtin_amdgcn_s_setprio(1); \
    _Pragma("unroll") \
    for (int ks = 0; ks < 2; ++ks) \
    _Pragma("unroll") \
    for (int ii = 0; ii < 4; ++ii) \
    _Pragma("unroll") \
    for (int jj = 0; jj < 2; ++jj) \
        acc[(IH) * 4 + ii][(JH) * 2 + jj] = __builtin_amdgcn_mfma_f32_16x16x32_bf16( \
            af[ii][ks], bfr[JH][jj][ks], acc[(IH) * 4 + ii][(JH) * 2 + jj], 0, 0, 0); \
    __builtin_amdgcn_s_setprio(0); \
} while (0)

// One K-tile. PRE: prefetch tile T+2 (k-elem KTN) into same buffer.
// VN: vmcnt arg at P3 (6 steady; 0 for tile 30). NXT: pre-read tile T+1 frags.
#define TILE(BUF, KTN, PRE, VN, NXT) do { \
    /* P1: quad (0,0) */ \
    BAR(); \
    if (PRE) { STG_A(BUF, 0, KTN); STG_A(BUF, 128, KTN); STG_B(BUF, 0, KTN); STG_B(BUF, 64, KTN); } \
    MMAQ(0, 0); \
    READ_B_(BUF, 1); \
    /* P2: quad (0,1) */ \
    BAR(); \
    if (PRE) { STG_B(BUF, 128, KTN); STG_B(BUF, 192, KTN); } \
    MMAQ(0, 1); \
    READ_A_(BUF, 1); \
    /* P3: quad (1,0) */ \
    WAITV(VN); \
    BAR(); \
    if (PRE) { STG_A(BUF, 64, KTN); STG_A(BUF, 192, KTN); } \
    MMAQ(1, 0); \
    if (NXT) READ_B_((BUF) ^ 1, 0); \
    /* P4: quad (1,1) */ \
    BAR(); \
    MMAQ(1, 1); \
    if (NXT) READ_A_((BUF) ^ 1, 0); \
} while (0)

#define TILE_LAST(BUF) do { \
    BAR(); MMAQ(0, 0); READ_B_(BUF, 1); \
    BAR(); MMAQ(0, 1); READ_A_(BUF, 1); \
    BAR(); MMAQ(1, 0); \
    MMAQ(1, 1); \
} while (0)

__global__ __launch_bounds__(512, 2) void gemm_main(
        const unsigned short* __restrict__ Aop,   // x bf16 [M][K]
        const unsigned short* __restrict__ Bop,   // Wt bf16 [N][K]
        int M, int N, int K,
        const float* __restrict__ bias,
        float* __restrict__ out) {
    __shared__ __align__(16) unsigned short ldsA[2][256 * 64];  // 2 x 32 KB
    __shared__ __align__(16) unsigned short ldsB[2][256 * 64];  // 2 x 32 KB

    const int t    = threadIdx.x;
    // XCD-aware bijective swizzle over the 8x64 grid (512 blocks, 512%8==0).
    const int flat = blockIdx.y * 8 + blockIdx.x;
    const int swz  = (flat & 7) * 64 + (flat >> 3);
    const int bn   = (swz & 7) * 256;
    const int bm   = (swz >> 3) * 256;
    const int lane = t & 63;
    const int wave = t >> 6;        // 0..7
    const int wm   = wave >> 2;     // 0..1
    const int wn   = wave & 3;      // 0..3
    const int waveM = wm * 128;
    const int fm = lane & 15;
    const int fq = lane >> 4;

    f32x4 acc[8][4];
#pragma unroll
    for (int i = 0; i < 8; ++i)
#pragma unroll
        for (int j = 0; j < 4; ++j)
            acc[i][j] = (f32x4){0.f, 0.f, 0.f, 0.f};

    short8 af[4][2];        // A frags, current i-half (single-buffered)
    short8 bfr[2][2][2];    // B frags per j-half (may hold different tiles)

    const int trow   = t >> 3;                  // 0..63
    const int tchunk = (t & 7) ^ (trow & 7);    // pre-swizzled source k-chunk
    const unsigned short* gA = Aop + (size_t)(bm + trow) * 2048 + tchunk * 8;
    const unsigned short* gB = Bop + (size_t)(bn + trow) * 2048 + tchunk * 8;

    // Prologue: stage tile 0 -> buf0 (8 oldest), tile 1 -> buf1.
    STG_A(0, 0, 0);   STG_A(0, 128, 0);  STG_B(0, 0, 0);   STG_B(0, 64, 0);
    STG_B(0, 128, 0); STG_B(0, 192, 0);  STG_A(0, 64, 0);  STG_A(0, 192, 0);
    STG_A(1, 0, 64);  STG_A(1, 128, 64); STG_B(1, 0, 64);  STG_B(1, 64, 64);
    STG_B(1, 128, 64);STG_B(1, 192, 64); STG_A(1, 64, 64); STG_A(1, 192, 64);
    WAITV(8);           // tile 0's 8 retired; tile 1's 8 in flight
    BAR();
    READ_A_(0, 0);      // af   = A0(tile 0)
    READ_B_(0, 0);      // bfr0 = B0(tile 0)

    // Main loop: tiles 0..29, full prefetch of tiles 2..31.
#pragma unroll 1
    for (int it = 0; it < 15; ++it) {
        const int kt = it * 128;
        TILE(0, kt + 128, 1, 6, 1);   // tile 2it,   prefetch 2it+2
        TILE(1, kt + 192, 1, 6, 1);   // tile 2it+1, prefetch 2it+3
    }
    // Tail: tile 30 (wait out tile 31's loads at P3), tile 31.
    TILE(0, 0, 0, 0, 1);
    TILE_LAST(1);

    // Epilogue: acc -> out (+bias). col mapping matches B frag remap.
#pragma unroll
    for (int i = 0; i < 8; ++i) {
        const int row0 = bm + waveM + i * 16 + fq * 4;
#pragma unroll
        for (int j = 0; j < 4; ++j) {
            const int col = bn + (j >> 1) * 128 + wn * 32 + (j & 1) * 16 + fm;
            const float b = bias[col];
#pragma unroll
            for (int r = 0; r < 4; ++r)
                out[(size_t)(row0 + r) * 2048 + col] = acc[i][j][r] + b;
        }
    }
}

extern "C" void kernel_launch(void* const* d_in, const int* in_sizes, int n_in,
                              void* d_out, int out_size, void* d_ws, size_t ws_size,
                              hipStream_t stream) {
    const float* x      = (const float*)d_in[0];   // 4*4096*2048
    const float* angles = (const float*)d_in[1];   // 2096128
    const float* bias   = (const float*)d_in[2];   // 2048
    float* out = (float*)d_out;

    char* ws = (char*)d_ws;
    unsigned short* Abf = (unsigned short*)ws;                      //  8 MB: A bf16
    unsigned short* Wt  = (unsigned short*)(ws + (8u << 20));       //  8 MB: W^T bf16
    unsigned short* xbf = (unsigned short*)(ws + (16u << 20));      // 64 MB: x bf16

    const int M = 4 * 4096;

    // prep: cvt x (32768 blocks) + build A (528 blocks), one launch
    prep_fused<<<NCVT + 528, 256, 0, stream>>>(x, xbf, angles, Abf);

    // Wt = I - 2A - A*A^T  (2048^3, 512 blocks of 128x64)
    gemm_s64<<<dim3(DIM / 64, DIM / 128), 256, 0, stream>>>(Abf, Wt);

    // out = x @ W + bias via NT against Wt (16384 x 2048 x 2048)
    gemm_main<<<dim3(DIM / 256, M / 256), 512, 0, stream>>>(
        xbf, Wt, M, DIM, DIM, bias, out);
}